// Round 19
// baseline (67.618 us; speedup 1.0000x reference)
//
#include <hip/hip_runtime.h>
#include <hip/hip_bf16.h>

#define D 512
#define BM 256
#define BKB 64                // K-tile bytes per row (64 i8 elements)
#define NKT 8                 // 512 / 64
#define NT 32                 // 8192 / 256
#define NBLK (NT*(NT+1)/2)    // 528 triangular blocks (528 = 8*66)
#define XCHUNK (NBLK/8)       // 66 blocks per XCD chunk
#define N2ROWS 8192

typedef __attribute__((ext_vector_type(4))) int i32x4;

// async global -> LDS, 16B per lane; LDS dest is wave-uniform base + lane*16
__device__ inline void gload16b(const char* g, char* l) {
    __builtin_amdgcn_global_load_lds(
        (const __attribute__((address_space(1))) unsigned int*)g,
        (__attribute__((address_space(3))) unsigned int*)l,
        16, 0, 0);
}

// Kernel A: row L2-norms, per-row-max int8 quantized Qn[2N][D], rscale[2N],
// pos[i]=exp(2*cos) in exact fp32; zeroes total.
__global__ __launch_bounds__(128) void prep_kernel(const float* __restrict__ y,
                                                   const float* __restrict__ yh,
                                                   char* __restrict__ Qn,
                                                   float* __restrict__ rscale,
                                                   float* __restrict__ pos,
                                                   float* __restrict__ total, int N) {
    const int i = blockIdx.x;
    const int t = threadIdx.x;
    if (i == 0 && t == 1) total[0] = 0.f;
    const float4 a = ((const float4*)(y + (size_t)i * D))[t];
    const float4 b = ((const float4*)(yh + (size_t)i * D))[t];
    float sy = a.x*a.x + a.y*a.y + a.z*a.z + a.w*a.w;
    float sh = b.x*b.x + b.y*b.y + b.z*b.z + b.w*b.w;
    float sd = a.x*b.x + a.y*b.y + a.z*b.z + a.w*b.w;
    float ma = fmaxf(fmaxf(fabsf(a.x), fabsf(a.y)), fmaxf(fabsf(a.z), fabsf(a.w)));
    float mb = fmaxf(fmaxf(fabsf(b.x), fabsf(b.y)), fmaxf(fabsf(b.z), fabsf(b.w)));
    #pragma unroll
    for (int o = 32; o > 0; o >>= 1) {
        sy += __shfl_xor(sy, o);
        sh += __shfl_xor(sh, o);
        sd += __shfl_xor(sd, o);
        ma = fmaxf(ma, __shfl_xor(ma, o));
        mb = fmaxf(mb, __shfl_xor(mb, o));
    }
    __shared__ float red[5][2];
    const int wv = t >> 6;
    if ((t & 63) == 0) { red[0][wv] = sy; red[1][wv] = sh; red[2][wv] = sd; red[3][wv] = ma; red[4][wv] = mb; }
    __syncthreads();
    sy = red[0][0] + red[0][1];
    sh = red[1][0] + red[1][1];
    sd = red[2][0] + red[2][1];
    ma = fmaxf(fmaxf(red[3][0], red[3][1]), 1e-20f);
    mb = fmaxf(fmaxf(red[4][0], red[4][1]), 1e-20f);
    const float ny = sqrtf(sy), nh = sqrtf(sh);
    const float ry = 1.f / fmaxf(ny, 1e-12f), rh = 1.f / fmaxf(nh, 1e-12f);
    const float qa = 127.f / ma, qb = 127.f / mb;
    const int ax = (int)rintf(a.x * qa), ay = (int)rintf(a.y * qa),
              az = (int)rintf(a.z * qa), aw = (int)rintf(a.w * qa);
    const int bx_ = (int)rintf(b.x * qb), by_ = (int)rintf(b.y * qb),
              bz = (int)rintf(b.z * qb), bw = (int)rintf(b.w * qb);
    const unsigned int pa = (ax & 0xff) | ((ay & 0xff) << 8) | ((az & 0xff) << 16) | ((aw & 0xff) << 24);
    const unsigned int pb = (bx_ & 0xff) | ((by_ & 0xff) << 8) | ((bz & 0xff) << 16) | ((bw & 0xff) << 24);
    ((unsigned int*)(Qn + (size_t)i * D))[t] = pa;
    ((unsigned int*)(Qn + (size_t)(i + N) * D))[t] = pb;
    if (t == 0) {
        rscale[i]     = ma * ry / 127.f;
        rscale[i + N] = mb * rh / 127.f;
        const float cs = sd / (fmaxf(ny, 1e-8f) * fmaxf(nh, 1e-8f));
        pos[i] = __expf(2.f * cs);
    }
}

// Kernel B: 256x256 tile, int8 K=64 MFMA. TRIPLE-BUFFERED 2-deep pipeline:
// iteration kt reads buf[kt%3], stages tile kt+2 into buf[(kt+2)%3], and at
// the end waits vmcnt(4) — completing tile kt+1, whose loads were issued a
// FULL iteration earlier (wait nearly always satisfied; the 2-buffer designs
// force-completed same-iteration loads = exposed L2 latency every tile).
// Race-freedom: staged buffer != read buffer (mod-3 disjoint); one s_barrier
// per iter separates iter kt-1's reads of buf[(kt-1)%3] from its overwrite.
// ds_reads issue BEFORE staging so DMA writes land during MFMA (conflict fix).
// Epilogue: dequant rscale[i]*rscale[j], exp, LDS combine, slab stores.
__global__ __launch_bounds__(512, 2) void simgemm_kernel(const char* __restrict__ Qn,
                                                         const float* __restrict__ rscale,
                                                         float* __restrict__ slab) {
    const int t0 = blockIdx.x;
    const int t = (t0 & 7) * XCHUNK + (t0 >> 3);
    int bx = (int)((sqrtf(8.f * (float)t + 1.f) - 1.f) * 0.5f);
    while ((bx + 1) * (bx + 2) / 2 <= t) ++bx;
    while (bx * (bx + 1) / 2 > t) --bx;
    const int by = t - bx * (bx + 1) / 2;

    __shared__ char As[3][BM * BKB];   // 3 x 16 KB
    __shared__ char Bs[3][BM * BKB];   // 3 x 16 KB
    __shared__ float redR[256][4];     // 4 KB
    __shared__ float redC[256][2];     // 2 KB   (102 KB total -> 1 block/CU)
    const int tid = threadIdx.x;
    const int lane = tid & 63;
    const int w = tid >> 6;
    const int wm = (w >> 2) * 128;
    const int wn = (w & 3) * 64;
    const int fr = lane & 15;
    const int fq = lane >> 4;
    const int rowA0 = by * BM, rowB0 = bx * BM;

    i32x4 acc[8][4] = {};

    const int srow = tid >> 2;
    const int scolb = (((tid & 3) ^ ((tid >> 4) & 3)) << 4);
    const int ldsoffb = w * 1024;

    const char* gA = Qn + (size_t)(rowA0 + srow) * D + scolb;
    const char* gB = Qn + (size_t)(rowB0 + srow) * D + scolb;

    auto SQA = [&](int buf, int k0, int q) {
        gload16b(gA + (size_t)q * 128 * D + k0, &As[buf][q * 8192 + ldsoffb]);
    };
    auto SQB = [&](int buf, int k0, int q) {
        gload16b(gB + (size_t)q * 128 * D + k0, &Bs[buf][q * 8192 + ldsoffb]);
    };
    auto ldA = [&](i32x4* dst, int cur, int rbase) {
        #pragma unroll
        for (int m = 0; m < 4; ++m) {
            const int row = rbase + m * 16 + fr;
            const int off = row * BKB + ((fq ^ ((row >> 2) & 3)) << 4);
            dst[m] = *(i32x4*)&As[cur][off];
        }
    };
    auto ldB = [&](i32x4* dst, int cur) {
        #pragma unroll
        for (int n = 0; n < 4; ++n) {
            const int row = wn + n * 16 + fr;
            const int off = row * BKB + ((fq ^ ((row >> 2) & 3)) << 4);
            dst[n] = *(i32x4*)&Bs[cur][off];
        }
    };

    // prologue: stage tiles 0 and 1
    #pragma unroll
    for (int q = 0; q < 2; ++q) { SQA(0, 0, q); SQB(0, 0, q); }
    #pragma unroll
    for (int q = 0; q < 2; ++q) { SQA(1, BKB, q); SQB(1, BKB, q); }
    asm volatile("s_waitcnt vmcnt(4)" ::: "memory");   // tile 0 landed; tile 1 in flight
    __builtin_amdgcn_s_barrier();

    for (int kt = 0; kt < NKT; ++kt) {
        const int cur = kt % 3;
        i32x4 af[4], ag[4], bb[4];
        ldA(af, cur, wm);
        ldB(bb, cur);
        ldA(ag, cur, wm + 64);
        __builtin_amdgcn_s_barrier();     // iter kt-1's reads of buf[(kt+2)%3] are done
        if (kt <= NKT - 3) {
            const int nb = (kt + 2) % 3, k2 = (kt + 2) * BKB;
            SQA(nb, k2, 0); SQA(nb, k2, 1);
            SQB(nb, k2, 0); SQB(nb, k2, 1);
        }
        __builtin_amdgcn_s_setprio(1);
        #pragma unroll
        for (int m = 0; m < 4; ++m)
            #pragma unroll
            for (int n = 0; n < 4; ++n)
                acc[m][n] = __builtin_amdgcn_mfma_i32_16x16x64_i8(af[m], bb[n], acc[m][n], 0, 0, 0);
        #pragma unroll
        for (int m = 0; m < 4; ++m)
            #pragma unroll
            for (int n = 0; n < 4; ++n)
                acc[m + 4][n] = __builtin_amdgcn_mfma_i32_16x16x64_i8(ag[m], bb[n], acc[m + 4][n], 0, 0, 0);
        __builtin_amdgcn_s_setprio(0);
        // complete tile kt+1 (issued one full iteration ago); keep kt+2 in flight
        if (kt <= NKT - 3)      asm volatile("s_waitcnt vmcnt(4)" ::: "memory");
        else if (kt == NKT - 2) asm volatile("s_waitcnt vmcnt(0)" ::: "memory");
    }

    const bool diagblk = (bx == by);
    // dequant + exp + fused row/col partial sums
    float rsb4[4];
    #pragma unroll
    for (int n = 0; n < 4; ++n) rsb4[n] = rscale[rowB0 + wn + n * 16 + fr];
    float colv[4] = {0.f, 0.f, 0.f, 0.f};
    #pragma unroll
    for (int m = 0; m < 8; ++m)
        #pragma unroll
        for (int r = 0; r < 4; ++r) {
            const int grow = wm + m * 16 + fq * 4 + r;
            const float rsa = rscale[rowA0 + grow];
            float rv = 0.f;
            #pragma unroll
            for (int n = 0; n < 4; ++n) {
                const float f = (float)acc[m][n][r] * rsa * rsb4[n];
                float e = __expf(2.f * f);
                const bool diag = diagblk && grow == (wn + n * 16 + fr);
                e = diag ? 0.f : e;
                rv += e;
                colv[n] += e;
            }
            rv += __shfl_xor(rv, 1);
            rv += __shfl_xor(rv, 2);
            rv += __shfl_xor(rv, 4);
            rv += __shfl_xor(rv, 8);
            if (fr == 0) redR[grow][w & 3] = rv;
        }
    if (!diagblk) {
        #pragma unroll
        for (int n = 0; n < 4; ++n) {
            float v = colv[n];
            v += __shfl_xor(v, 16);
            v += __shfl_xor(v, 32);
            if (fq == 0) redC[wn + n * 16 + fr][w >> 2] = v;
        }
    }
    __syncthreads();
    if (tid < 256) {
        const float v = redR[tid][0] + redR[tid][1] + redR[tid][2] + redR[tid][3];
        slab[(size_t)bx * N2ROWS + rowA0 + tid] = v;
    } else if (!diagblk) {
        const int c = tid - 256;
        const float v = redC[c][0] + redC[c][1];
        slab[(size_t)by * N2ROWS + rowB0 + c] = v;
    }
}

// Kernel C1: per-row neg = sum of 32 partials; s = pos/neg; block-reduce; 32 atomics
__global__ __launch_bounds__(256) void reduce_kernel(const float* __restrict__ slab,
                                                     const float* __restrict__ pos,
                                                     float* __restrict__ total, int N) {
    const int i = blockIdx.x * 256 + threadIdx.x;   // 0..8191
    float neg = 0.f;
    #pragma unroll
    for (int q = 0; q < NT; ++q) neg += slab[(size_t)q * N2ROWS + i];
    const float p = pos[i < N ? i : i - N];
    float s = p / neg;
    #pragma unroll
    for (int o = 32; o > 0; o >>= 1) s += __shfl_xor(s, o);
    __shared__ float red[4];
    if ((threadIdx.x & 63) == 0) red[threadIdx.x >> 6] = s;
    __syncthreads();
    if (threadIdx.x == 0) atomicAdd(total, red[0] + red[1] + red[2] + red[3]);
}

// Kernel C2: loss = log(2N) - log(total)
__global__ void final_kernel(const float* __restrict__ total,
                             float* __restrict__ out, int N) {
    out[0] = logf(2.f * (float)N) - logf(total[0]);
}

extern "C" void kernel_launch(void* const* d_in, const int* in_sizes, int n_in,
                              void* d_out, int out_size, void* d_ws, size_t ws_size,
                              hipStream_t stream) {
    const float* y  = (const float*)d_in[0];
    const float* yh = (const float*)d_in[1];
    const int N  = in_sizes[0] / D;   // 4096
    const int N2 = 2 * N;             // 8192

    char* Qn = (char*)d_ws;                                      // [2N][D] i8, 4 MB
    const size_t qn_bytes = (size_t)N2 * D;
    float* slab   = (float*)((char*)d_ws + qn_bytes);            // [32][8192] = 1 MB
    float* pos    = slab + (size_t)NT * N2ROWS;                  // [N]
    float* total  = pos + N;                                     // [1]
    float* rscale = total + 1;                                   // [2N]
    float* out = (float*)d_out;

    prep_kernel<<<N, 128, 0, stream>>>(y, yh, Qn, rscale, pos, total, N);
    simgemm_kernel<<<NBLK, 512, 0, stream>>>(Qn, rscale, slab);
    reduce_kernel<<<N2 / 256, 256, 0, stream>>>(slab, pos, total, N);
    final_kernel<<<1, 1, 0, stream>>>(total, out, N);
}

// Round 20
// 67.011 us; speedup vs baseline: 1.0091x; 1.0091x over previous
//
#include <hip/hip_runtime.h>
#include <hip/hip_bf16.h>

#define D 512
#define BM 256
#define BKB 64                // K-tile bytes per row (64 i8 elements)
#define NKT 8                 // 512 / 64
#define NT 32                 // 8192 / 256
#define NBLK (NT*(NT+1)/2)    // 528 triangular blocks (528 = 8*66)
#define XCHUNK (NBLK/8)       // 66 blocks per XCD chunk
#define N2ROWS 8192
#define ABYTES (BM*BKB)       // 16384 per buffer

typedef __attribute__((ext_vector_type(4))) int i32x4;

// async global -> LDS, 16B per lane; LDS dest is wave-uniform base + lane*16
__device__ inline void gload16b(const char* g, char* l) {
    __builtin_amdgcn_global_load_lds(
        (const __attribute__((address_space(1))) unsigned int*)g,
        (__attribute__((address_space(3))) unsigned int*)l,
        16, 0, 0);
}

// Kernel A: 4 rows per block (512 thr). Row L2-norms, per-row-max int8 quant
// Qn[2N][D], rscale[2N], pos[i]=exp(2*cos) fp32; zeroes total+ticket.
__global__ __launch_bounds__(512) void prep_kernel(const float* __restrict__ y,
                                                   const float* __restrict__ yh,
                                                   char* __restrict__ Qn,
                                                   float* __restrict__ rscale,
                                                   float* __restrict__ pos,
                                                   float* __restrict__ total,
                                                   int* __restrict__ ticket, int N) {
    const int t = threadIdx.x;
    const int g = t >> 7;           // row-group 0..3
    const int tl = t & 127;         // lane within group
    const int i = blockIdx.x * 4 + g;
    if (blockIdx.x == 0) {
        if (t == 0) total[0] = 0.f;
        if (t == 1) ticket[0] = 0;
    }
    const float4 a = ((const float4*)(y + (size_t)i * D))[tl];
    const float4 b = ((const float4*)(yh + (size_t)i * D))[tl];
    float sy = a.x*a.x + a.y*a.y + a.z*a.z + a.w*a.w;
    float sh = b.x*b.x + b.y*b.y + b.z*b.z + b.w*b.w;
    float sd = a.x*b.x + a.y*b.y + a.z*b.z + a.w*b.w;
    float ma = fmaxf(fmaxf(fabsf(a.x), fabsf(a.y)), fmaxf(fabsf(a.z), fabsf(a.w)));
    float mb = fmaxf(fmaxf(fabsf(b.x), fabsf(b.y)), fmaxf(fabsf(b.z), fabsf(b.w)));
    #pragma unroll
    for (int o = 32; o > 0; o >>= 1) {
        sy += __shfl_xor(sy, o);
        sh += __shfl_xor(sh, o);
        sd += __shfl_xor(sd, o);
        ma = fmaxf(ma, __shfl_xor(ma, o));
        mb = fmaxf(mb, __shfl_xor(mb, o));
    }
    __shared__ float red[4][5][2];
    const int wv = tl >> 6;
    if ((tl & 63) == 0) {
        red[g][0][wv] = sy; red[g][1][wv] = sh; red[g][2][wv] = sd;
        red[g][3][wv] = ma; red[g][4][wv] = mb;
    }
    __syncthreads();
    sy = red[g][0][0] + red[g][0][1];
    sh = red[g][1][0] + red[g][1][1];
    sd = red[g][2][0] + red[g][2][1];
    ma = fmaxf(fmaxf(red[g][3][0], red[g][3][1]), 1e-20f);
    mb = fmaxf(fmaxf(red[g][4][0], red[g][4][1]), 1e-20f);
    const float ny = sqrtf(sy), nh = sqrtf(sh);
    const float ry = 1.f / fmaxf(ny, 1e-12f), rh = 1.f / fmaxf(nh, 1e-12f);
    const float qa = 127.f / ma, qb = 127.f / mb;
    const int ax = (int)rintf(a.x * qa), ay = (int)rintf(a.y * qa),
              az = (int)rintf(a.z * qa), aw = (int)rintf(a.w * qa);
    const int bx_ = (int)rintf(b.x * qb), by_ = (int)rintf(b.y * qb),
              bz = (int)rintf(b.z * qb), bw = (int)rintf(b.w * qb);
    const unsigned int pa = (ax & 0xff) | ((ay & 0xff) << 8) | ((az & 0xff) << 16) | ((aw & 0xff) << 24);
    const unsigned int pb = (bx_ & 0xff) | ((by_ & 0xff) << 8) | ((bz & 0xff) << 16) | ((bw & 0xff) << 24);
    ((unsigned int*)(Qn + (size_t)i * D))[tl] = pa;
    ((unsigned int*)(Qn + (size_t)(i + N) * D))[tl] = pb;
    if (tl == 0) {
        rscale[i]     = ma * ry / 127.f;
        rscale[i + N] = mb * rh / 127.f;
        const float cs = sd / (fmaxf(ny, 1e-8f) * fmaxf(nh, 1e-8f));
        pos[i] = __expf(2.f * cs);
    }
}

// Kernel B: R19 core (256x256, i8 K=64 MFMA, triple-buffer 2-deep counted
// vmcnt) with ds_read addressing HOISTED: the 12 per-lane swizzled offsets
// are loop-invariant — precomputed once; in-loop reads are base+offset only.
__global__ __launch_bounds__(512, 2) void simgemm_kernel(const char* __restrict__ Qn,
                                                         const float* __restrict__ rscale,
                                                         float* __restrict__ slab) {
    const int t0 = blockIdx.x;
    const int t = (t0 & 7) * XCHUNK + (t0 >> 3);
    int bx = (int)((sqrtf(8.f * (float)t + 1.f) - 1.f) * 0.5f);
    while ((bx + 1) * (bx + 2) / 2 <= t) ++bx;
    while (bx * (bx + 1) / 2 > t) --bx;
    const int by = t - bx * (bx + 1) / 2;

    __shared__ char As[3 * ABYTES];    // 48 KB
    __shared__ char Bs[3 * ABYTES];    // 48 KB
    __shared__ float redR[256][4];     // 4 KB
    __shared__ float redC[256][2];     // 2 KB  (102 KB -> 1 block/CU)
    const int tid = threadIdx.x;
    const int lane = tid & 63;
    const int w = tid >> 6;
    const int wm = (w >> 2) * 128;
    const int wn = (w & 3) * 64;
    const int fr = lane & 15;
    const int fq = lane >> 4;
    const int rowA0 = by * BM, rowB0 = bx * BM;

    i32x4 acc[8][4] = {};

    // hoisted per-lane ds_read byte offsets (loop-invariant)
    int offA[8], offB[4];
    #pragma unroll
    for (int m = 0; m < 8; ++m) {
        const int row = wm + (m >> 2) * 64 + (m & 3) * 16 + fr;
        offA[m] = row * BKB + ((fq ^ ((row >> 2) & 3)) << 4);
    }
    #pragma unroll
    for (int n = 0; n < 4; ++n) {
        const int row = wn + n * 16 + fr;
        offB[n] = row * BKB + ((fq ^ ((row >> 2) & 3)) << 4);
    }

    const int srow = tid >> 2;
    const int scolb = (((tid & 3) ^ ((tid >> 4) & 3)) << 4);
    const int ldsoffb = w * 1024;

    const char* gA = Qn + (size_t)(rowA0 + srow) * D + scolb;
    const char* gB = Qn + (size_t)(rowB0 + srow) * D + scolb;

    auto SQA = [&](int buf, int k0, int q) {
        gload16b(gA + (size_t)q * 128 * D + k0, As + buf * ABYTES + q * 8192 + ldsoffb);
    };
    auto SQB = [&](int buf, int k0, int q) {
        gload16b(gB + (size_t)q * 128 * D + k0, Bs + buf * ABYTES + q * 8192 + ldsoffb);
    };

    // prologue: stage tiles 0 and 1
    #pragma unroll
    for (int q = 0; q < 2; ++q) { SQA(0, 0, q); SQB(0, 0, q); }
    #pragma unroll
    for (int q = 0; q < 2; ++q) { SQA(1, BKB, q); SQB(1, BKB, q); }
    asm volatile("s_waitcnt vmcnt(4)" ::: "memory");   // tile 0 landed; tile 1 in flight
    __builtin_amdgcn_s_barrier();

    for (int kt = 0; kt < NKT; ++kt) {
        const int cur = kt % 3;
        const char* ab = As + cur * ABYTES;
        const char* bbse = Bs + cur * ABYTES;
        i32x4 fa[8], bb[4];
        #pragma unroll
        for (int m = 0; m < 8; ++m) fa[m] = *(const i32x4*)(ab + offA[m]);
        #pragma unroll
        for (int n = 0; n < 4; ++n) bb[n] = *(const i32x4*)(bbse + offB[n]);
        __builtin_amdgcn_s_barrier();     // prev iter's reads of the stage target done
        if (kt <= NKT - 3) {
            const int nb = (kt + 2) % 3, k2 = (kt + 2) * BKB;
            SQA(nb, k2, 0); SQA(nb, k2, 1);
            SQB(nb, k2, 0); SQB(nb, k2, 1);
        }
        __builtin_amdgcn_s_setprio(1);
        #pragma unroll
        for (int m = 0; m < 4; ++m)
            #pragma unroll
            for (int n = 0; n < 4; ++n)
                acc[m][n] = __builtin_amdgcn_mfma_i32_16x16x64_i8(fa[m], bb[n], acc[m][n], 0, 0, 0);
        #pragma unroll
        for (int m = 0; m < 4; ++m)
            #pragma unroll
            for (int n = 0; n < 4; ++n)
                acc[m + 4][n] = __builtin_amdgcn_mfma_i32_16x16x64_i8(fa[m + 4], bb[n], acc[m + 4][n], 0, 0, 0);
        __builtin_amdgcn_s_setprio(0);
        // complete tile kt+1 (issued one full iteration ago); keep kt+2 in flight
        if (kt <= NKT - 3)      asm volatile("s_waitcnt vmcnt(4)" ::: "memory");
        else if (kt == NKT - 2) asm volatile("s_waitcnt vmcnt(0)" ::: "memory");
    }

    const bool diagblk = (bx == by);
    // dequant + exp + fused row/col partial sums
    float rsb4[4];
    #pragma unroll
    for (int n = 0; n < 4; ++n) rsb4[n] = rscale[rowB0 + wn + n * 16 + fr];
    float colv[4] = {0.f, 0.f, 0.f, 0.f};
    #pragma unroll
    for (int m = 0; m < 8; ++m)
        #pragma unroll
        for (int r = 0; r < 4; ++r) {
            const int grow = wm + m * 16 + fq * 4 + r;
            const float rsa = rscale[rowA0 + grow];
            float rv = 0.f;
            #pragma unroll
            for (int n = 0; n < 4; ++n) {
                const float f = (float)acc[m][n][r] * rsa * rsb4[n];
                float e = __expf(2.f * f);
                const bool diag = diagblk && grow == (wn + n * 16 + fr);
                e = diag ? 0.f : e;
                rv += e;
                colv[n] += e;
            }
            rv += __shfl_xor(rv, 1);
            rv += __shfl_xor(rv, 2);
            rv += __shfl_xor(rv, 4);
            rv += __shfl_xor(rv, 8);
            if (fr == 0) redR[grow][w & 3] = rv;
        }
    if (!diagblk) {
        #pragma unroll
        for (int n = 0; n < 4; ++n) {
            float v = colv[n];
            v += __shfl_xor(v, 16);
            v += __shfl_xor(v, 32);
            if (fq == 0) redC[wn + n * 16 + fr][w >> 2] = v;
        }
    }
    __syncthreads();
    if (tid < 256) {
        const float v = redR[tid][0] + redR[tid][1] + redR[tid][2] + redR[tid][3];
        slab[(size_t)bx * N2ROWS + rowA0 + tid] = v;
    } else if (!diagblk) {
        const int c = tid - 256;
        const float v = redC[c][0] + redC[c][1];
        slab[(size_t)by * N2ROWS + rowB0 + c] = v;
    }
}

// Kernel C (fused): per-row neg, s = pos/neg, block reduce, atomic total;
// the LAST block (device-scope ticket) computes the final loss.
__global__ __launch_bounds__(256) void reduce_kernel(const float* __restrict__ slab,
                                                     const float* __restrict__ pos,
                                                     float* __restrict__ total,
                                                     int* __restrict__ ticket,
                                                     float* __restrict__ out, int N) {
    const int i = blockIdx.x * 256 + threadIdx.x;   // 0..8191
    float neg = 0.f;
    #pragma unroll
    for (int q = 0; q < NT; ++q) neg += slab[(size_t)q * N2ROWS + i];
    const float p = pos[i < N ? i : i - N];
    float s = p / neg;
    #pragma unroll
    for (int o = 32; o > 0; o >>= 1) s += __shfl_xor(s, o);
    __shared__ float red[4];
    if ((threadIdx.x & 63) == 0) red[threadIdx.x >> 6] = s;
    __syncthreads();
    if (threadIdx.x == 0) {
        atomicAdd(total, red[0] + red[1] + red[2] + red[3]);
        __threadfence();
        const int my = atomicAdd(ticket, 1);
        if (my == gridDim.x - 1) {
            const float tot = atomicAdd(total, 0.f);   // device-scope read after all adds
            out[0] = logf(2.f * (float)N) - logf(tot);
        }
    }
}

extern "C" void kernel_launch(void* const* d_in, const int* in_sizes, int n_in,
                              void* d_out, int out_size, void* d_ws, size_t ws_size,
                              hipStream_t stream) {
    const float* y  = (const float*)d_in[0];
    const float* yh = (const float*)d_in[1];
    const int N  = in_sizes[0] / D;   // 4096
    const int N2 = 2 * N;             // 8192

    char* Qn = (char*)d_ws;                                      // [2N][D] i8, 4 MB
    const size_t qn_bytes = (size_t)N2 * D;
    float* slab   = (float*)((char*)d_ws + qn_bytes);            // [32][8192] = 1 MB
    float* pos    = slab + (size_t)NT * N2ROWS;                  // [N]
    float* total  = pos + N;                                     // [1]
    float* rscale = total + 1;                                   // [2N]
    int*   ticket = (int*)(rscale + N2);                         // [1]
    float* out = (float*)d_out;

    prep_kernel<<<N / 4, 512, 0, stream>>>(y, yh, Qn, rscale, pos, total, ticket, N);
    simgemm_kernel<<<NBLK, 512, 0, stream>>>(Qn, rscale, slab);
    reduce_kernel<<<N2 / 256, 256, 0, stream>>>(slab, pos, total, ticket, out, N);
}